// Round 1
// 206.632 us; speedup vs baseline: 1.1429x; 1.1429x over previous
//
#include <hip/hip_runtime.h>
#include <hip/hip_bf16.h>

#define N_NODES 50000
#define N_EDGES 800000
#define IN_F 128
#define OUT_F 128
#define TOPK 32
#define MAXDEG 64   // Poisson(16) tail at 64 ~1e-15; guarded below

typedef __attribute__((ext_vector_type(8))) short short8;
typedef __attribute__((ext_vector_type(4))) float f32x4;

static __device__ inline unsigned short f2bf(float x) {
    __hip_bfloat16 h = __float2bfloat16(x);
    return *reinterpret_cast<unsigned short*>(&h);
}

// ---------------------------------------------------------------------------
// Kernel 1: pure edge scatter into padded CSR. (The per-node pack/win-check
// work is gone: the x_sparse tile is now built in-LDS inside the GEMM kernel.)
// ---------------------------------------------------------------------------
__global__ void scatter_kernel(const int* __restrict__ src, const int* __restrict__ dst,
                               int* __restrict__ deg, int* __restrict__ esrc_pad, int E) {
    int t = blockIdx.x * blockDim.x + threadIdx.x;
    if (t < E) {
        int d = dst[t];
        int r = atomicAdd(&deg[d], 1);
        if (r < MAXDEG) esrc_pad[d * MAXDEG + r] = src[t];
    }
}

// ---------------------------------------------------------------------------
// Kernel 2: TWO MFMA GEMMs, one per block-half.
//   blocks [0, GEMB):      out  = feat @ Ws + b          (A = f32, convert)
//   blocks [GEMB, 2*GEMB): y_bf = x_sparse @ Wn (bf16)   (A built in LDS from topk)
// x_sparse tile build: thread t<128 owns node rowbase+t, scatters its 32
// bf16 values into a zeroed LDS row with ascending-k overwrite = last-wins
// (identical semantics to the old win-check). XS_PAD=152 keeps ds_read_b128
// 16B-aligned (304B row stride) and gives ~2-way max bank aliasing (free).
// ---------------------------------------------------------------------------
#define GEMB ((N_NODES + 127) / 128)   // 391
#define BK_PAD 136
#define XS_PAD 152
__global__ __launch_bounds__(256) void gemm2_kernel(
    const float* __restrict__ feat, const float* __restrict__ Ws,
    const float* __restrict__ bias, float* __restrict__ out,
    const float* __restrict__ vals, const int* __restrict__ topk_idx,
    const float* __restrict__ Wn, unsigned short* __restrict__ y_bf, int n) {
    __shared__ unsigned short BL[128 * BK_PAD];    // 34.8 KB B-tile (Ws or Wn)
    __shared__ unsigned short XSL[128 * XS_PAD];   // 38.9 KB A-tile (x_sparse)
    int t = threadIdx.x;
    bool self = (blockIdx.x < GEMB);
    int bx = self ? blockIdx.x : (blockIdx.x - GEMB);
    int rowbase_blk = bx * 128;

    // ---- stage B transposed: BL[col][k] = W[k][col] as bf16 ----
    {
        const float* W = self ? Ws : Wn;
        int col = t & 127;
        int kh = t >> 7;
        unsigned short* dstp = &BL[col * BK_PAD + kh * 64];
        const float* Wp = W + (size_t)kh * 64 * OUT_F + col;
#pragma unroll 4
        for (int kk = 0; kk < 64; kk += 2) {
            float w0 = Wp[kk * OUT_F];
            float w1 = Wp[(kk + 1) * OUT_F];
            *(unsigned*)&dstp[kk] = (unsigned)f2bf(w0) | ((unsigned)f2bf(w1) << 16);
        }
    }

    if (!self) {
        // ---- build x_sparse tile in LDS ----
        unsigned* xz = (unsigned*)XSL;
#pragma unroll 4
        for (int i = t; i < 128 * XS_PAD / 2; i += 256) xz[i] = 0u;
        __syncthreads();  // zeroing (all threads) before scatter (t<128)
        if (t < 128) {
            int node = rowbase_blk + t;
            if (node < n) {
                int idx[TOPK];
                float v[TOPK];
#pragma unroll
                for (int k = 0; k < TOPK; k += 4) {
                    *(int4*)&idx[k]  = *(const int4*)&topk_idx[(size_t)node * TOPK + k];
                    *(float4*)&v[k]  = *(const float4*)&vals[(size_t)node * TOPK + k];
                }
                unsigned short* rowp = &XSL[t * XS_PAD];
#pragma unroll
                for (int k = 0; k < TOPK; ++k)
                    rowp[idx[k] & 127] = f2bf(v[k]);   // program order => last k wins
            }
        }
    }
    __syncthreads();

    int wave = t >> 6;
    int lane = t & 63;
    int quad = lane >> 4;
    int lq = lane & 15;
    int rowbase = rowbase_blk + wave * 32;
    int r0 = rowbase + lq;
    int r1 = rowbase + 16 + lq;

    f32x4 acc0[8], acc1[8];
#pragma unroll
    for (int i = 0; i < 8; ++i) { acc0[i] = (f32x4){0,0,0,0}; acc1[i] = (f32x4){0,0,0,0}; }

#pragma unroll
    for (int ks = 0; ks < 4; ++ks) {
        int k0 = ks * 32 + quad * 8;
        short8 a0, a1;
        if (self) {
            float4 z = {0.f, 0.f, 0.f, 0.f};
            float4 f00 = (r0 < n) ? *(const float4*)&feat[r0 * IN_F + k0] : z;
            float4 f01 = (r0 < n) ? *(const float4*)&feat[r0 * IN_F + k0 + 4] : z;
            float4 f10 = (r1 < n) ? *(const float4*)&feat[r1 * IN_F + k0] : z;
            float4 f11 = (r1 < n) ? *(const float4*)&feat[r1 * IN_F + k0 + 4] : z;
            union { short8 s; unsigned short u[8]; } ua, ub;
            ua.u[0] = f2bf(f00.x); ua.u[1] = f2bf(f00.y); ua.u[2] = f2bf(f00.z); ua.u[3] = f2bf(f00.w);
            ua.u[4] = f2bf(f01.x); ua.u[5] = f2bf(f01.y); ua.u[6] = f2bf(f01.z); ua.u[7] = f2bf(f01.w);
            ub.u[0] = f2bf(f10.x); ub.u[1] = f2bf(f10.y); ub.u[2] = f2bf(f10.z); ub.u[3] = f2bf(f10.w);
            ub.u[4] = f2bf(f11.x); ub.u[5] = f2bf(f11.y); ub.u[6] = f2bf(f11.z); ub.u[7] = f2bf(f11.w);
            a0 = ua.s; a1 = ub.s;
        } else {
            int lr0 = wave * 32 + lq;
            a0 = *(const short8*)&XSL[lr0 * XS_PAD + k0];
            a1 = *(const short8*)&XSL[(lr0 + 16) * XS_PAD + k0];
        }
#pragma unroll
        for (int nt = 0; nt < 8; ++nt) {
            short8 b = *(const short8*)&BL[(nt * 16 + lq) * BK_PAD + k0];
            acc0[nt] = __builtin_amdgcn_mfma_f32_16x16x32_bf16(a0, b, acc0[nt], 0, 0, 0);
            acc1[nt] = __builtin_amdgcn_mfma_f32_16x16x32_bf16(a1, b, acc1[nt], 0, 0, 0);
        }
    }

    if (self) {
#pragma unroll
        for (int nt = 0; nt < 8; ++nt) {
            int col = nt * 16 + lq;
            float bb = bias[col];
#pragma unroll
            for (int r = 0; r < 4; ++r) {
                int row = rowbase + quad * 4 + r;
                if (row < n) out[row * OUT_F + col] = acc0[nt][r] + bb;
                int row2 = row + 16;
                if (row2 < n) out[row2 * OUT_F + col] = acc1[nt][r] + bb;
            }
        }
    } else {
        // y stored row-major bf16: u32 at [node*64+l] = cols {2l (lo), 2l+1 (hi)}
        // -> bit-identical layout to the old y_u for the unchanged agg kernel.
#pragma unroll
        for (int nt = 0; nt < 8; ++nt) {
            int col = nt * 16 + lq;
#pragma unroll
            for (int r = 0; r < 4; ++r) {
                int row = rowbase + quad * 4 + r;
                if (row < n) y_bf[row * OUT_F + col] = f2bf(acc0[nt][r]);
                int row2 = row + 16;
                if (row2 < n) y_bf[row2 * OUT_F + col] = f2bf(acc1[nt][r]);
            }
        }
    }
}

// ---------------------------------------------------------------------------
// Kernel 3 (finalizer, unchanged apart from MAXDEG): out[d] += (1/deg) * sum y[src].
// ---------------------------------------------------------------------------
#define AGG_BLOCKS 2048
__global__ __launch_bounds__(256) void agg_out_kernel(
    const int* __restrict__ deg, const int* __restrict__ esrc_pad,
    const unsigned* __restrict__ y_u, float* __restrict__ out, int n) {
    int wid = (blockIdx.x * 256 + threadIdx.x) >> 6;
    int l = threadIdx.x & 63;
    int nwaves = AGG_BLOCKS * 4;

    for (int d = wid; d < n; d += nwaves) {
        int bc_all = min(deg[d], MAXDEG);
        const int* row = esrc_pad + d * MAXDEG;
        float2 acc = {0.f, 0.f};
        for (int base = 0; base < bc_all; base += 64) {
            int bc = min(bc_all - base, 64);
            int sv = row[base + min(l, bc - 1)];  // one coalesced batch load
            for (int r = 0; r < bc; r += 8) {
                unsigned uu[8];
                float mm[8];
#pragma unroll
                for (int q = 0; q < 8; ++q) {
                    int rr = r + q;
                    mm[q] = (rr < bc) ? 1.f : 0.f;
                    int s = __shfl(sv, min(rr, bc - 1));
                    uu[q] = y_u[s * 64 + l];
                }
#pragma unroll
                for (int q = 0; q < 8; ++q) {
                    acc.x += __uint_as_float(uu[q] << 16) * mm[q];
                    acc.y += __uint_as_float(uu[q] & 0xffff0000u) * mm[q];
                }
            }
        }
        float inv = 1.0f / (float)max(bc_all, 1);
        float2 cur = *(float2*)&out[d * OUT_F + 2 * l];
        cur.x += acc.x * inv;
        cur.y += acc.y * inv;
        *(float2*)&out[d * OUT_F + 2 * l] = cur;
    }
}

// ---------------------------------------------------------------------------
extern "C" void kernel_launch(void* const* d_in, const int* in_sizes, int n_in,
                              void* d_out, int out_size, void* d_ws, size_t ws_size,
                              hipStream_t stream) {
    const float* feat    = (const float*)d_in[0];
    const float* vals    = (const float*)d_in[1];
    const int*   idxs    = (const int*)d_in[2];
    const int*   src     = (const int*)d_in[3];
    const int*   dst     = (const int*)d_in[4];
    const float* W_self  = (const float*)d_in[5];
    const float* b_self  = (const float*)d_in[6];
    const float* W_neigh = (const float*)d_in[7];
    float*       out     = (float*)d_out;

    const int n = N_NODES;
    const int E = N_EDGES;

    // Workspace: [deg N][y_bf N*128 bf16][esrc_pad N*64 i32]  (~25.8 MB)
    char* p = (char*)d_ws;
    int*            deg      = (int*)p;            p += (size_t)n * sizeof(int);
    unsigned short* y_bf     = (unsigned short*)p; p += (size_t)n * OUT_F * sizeof(unsigned short);
    int*            esrc_pad = (int*)p;

    hipMemsetAsync(deg, 0, (size_t)n * sizeof(int), stream);

    scatter_kernel<<<(E + 255) / 256, 256, 0, stream>>>(src, dst, deg, esrc_pad, E);
    gemm2_kernel<<<2 * GEMB, 256, 0, stream>>>(
        feat, W_self, b_self, out, vals, idxs, W_neigh, y_bf, n);
    agg_out_kernel<<<AGG_BLOCKS, 256, 0, stream>>>(deg, esrc_pad, (const unsigned*)y_bf, out, n);
}

// Round 2
// 201.473 us; speedup vs baseline: 1.1721x; 1.0256x over previous
//
#include <hip/hip_runtime.h>
#include <hip/hip_bf16.h>

#define N_NODES 50000
#define N_EDGES 800000
#define IN_F 128
#define OUT_F 128
#define TOPK 32
#define MAXDEG 64   // Poisson(16) tail at 64 ~1e-15; guarded below

typedef __attribute__((ext_vector_type(8))) short short8;
typedef __attribute__((ext_vector_type(4))) float f32x4;

static __device__ inline unsigned short f2bf(float x) {
    __hip_bfloat16 h = __float2bfloat16(x);
    return *reinterpret_cast<unsigned short*>(&h);
}

// ---------------------------------------------------------------------------
// Kernel 1 (FUSED): edge-scatter prologue + TWO MFMA GEMMs.
//   all blocks:            scatter 1024 edges into padded CSR (latency/write
//                          bound, 0.4% VALU -> hides under the MFMA GEMM)
//   blocks [0, GEMB):      out  = feat @ Ws + b
//   blocks [GEMB, 2*GEMB): y_bf = x_sparse @ Wn   (A built in LDS from topk)
// deg_pad: one counter per 64B line (stride 16 ints) -> no cross-XCD atomic
// line ping-pong between distinct nodes. esrc_pad is ushort (src < 65536):
// halves the scattered-write footprint (128B rows).
// ---------------------------------------------------------------------------
#define GEMB ((N_NODES + 127) / 128)   // 391
#define BK_PAD 136
#define XS_PAD 152
__global__ __launch_bounds__(256) void gemm2_scatter_kernel(
    const float* __restrict__ feat, const float* __restrict__ Ws,
    const float* __restrict__ bias, float* __restrict__ out,
    const float* __restrict__ vals, const int* __restrict__ topk_idx,
    const float* __restrict__ Wn, unsigned short* __restrict__ y_bf,
    const int* __restrict__ src, const int* __restrict__ dst,
    int* __restrict__ deg_pad, unsigned short* __restrict__ esrc_pad,
    int n, int E) {
    __shared__ unsigned short BL[128 * BK_PAD];    // 34.8 KB B-tile (Ws or Wn)
    __shared__ unsigned short XSL[128 * XS_PAD];   // 38.9 KB A-tile (x_sparse)
    int t = threadIdx.x;

    // ---- edge-scatter prologue: 4 edges/thread, coalesced chunk of 1024 ----
    {
        int e0 = blockIdx.x * 1024 + t;
        int es[4], ed[4];
#pragma unroll
        for (int q = 0; q < 4; ++q) {
            int e = e0 + q * 256;
            bool ok = (e < E);
            es[q] = ok ? src[e] : 0;
            ed[q] = ok ? dst[e] : -1;
        }
#pragma unroll
        for (int q = 0; q < 4; ++q) {
            if (ed[q] >= 0) {
                int r = atomicAdd(&deg_pad[ed[q] << 4], 1);
                if (r < MAXDEG)
                    esrc_pad[ed[q] * MAXDEG + r] = (unsigned short)es[q];
            }
        }
    }

    bool self = (blockIdx.x < GEMB);
    int bx = self ? blockIdx.x : (blockIdx.x - GEMB);
    int rowbase_blk = bx * 128;

    // ---- stage B transposed: BL[col][k] = W[k][col] as bf16 ----
    {
        const float* W = self ? Ws : Wn;
        int col = t & 127;
        int kh = t >> 7;
        unsigned short* dstp = &BL[col * BK_PAD + kh * 64];
        const float* Wp = W + (size_t)kh * 64 * OUT_F + col;
#pragma unroll 4
        for (int kk = 0; kk < 64; kk += 2) {
            float w0 = Wp[kk * OUT_F];
            float w1 = Wp[(kk + 1) * OUT_F];
            *(unsigned*)&dstp[kk] = (unsigned)f2bf(w0) | ((unsigned)f2bf(w1) << 16);
        }
    }

    if (!self) {
        // ---- build x_sparse tile in LDS ----
        unsigned* xz = (unsigned*)XSL;
#pragma unroll 4
        for (int i = t; i < 128 * XS_PAD / 2; i += 256) xz[i] = 0u;
        __syncthreads();  // zeroing (all threads) before scatter (t<128)
        if (t < 128) {
            int node = rowbase_blk + t;
            if (node < n) {
                int idx[TOPK];
                float v[TOPK];
#pragma unroll
                for (int k = 0; k < TOPK; k += 4) {
                    *(int4*)&idx[k]  = *(const int4*)&topk_idx[(size_t)node * TOPK + k];
                    *(float4*)&v[k]  = *(const float4*)&vals[(size_t)node * TOPK + k];
                }
                unsigned short* rowp = &XSL[t * XS_PAD];
#pragma unroll
                for (int k = 0; k < TOPK; ++k)
                    rowp[idx[k] & 127] = f2bf(v[k]);   // program order => last k wins
            }
        }
    }
    __syncthreads();

    int wave = t >> 6;
    int lane = t & 63;
    int quad = lane >> 4;
    int lq = lane & 15;
    int rowbase = rowbase_blk + wave * 32;
    int r0 = rowbase + lq;
    int r1 = rowbase + 16 + lq;

    f32x4 acc0[8], acc1[8];
#pragma unroll
    for (int i = 0; i < 8; ++i) { acc0[i] = (f32x4){0,0,0,0}; acc1[i] = (f32x4){0,0,0,0}; }

#pragma unroll
    for (int ks = 0; ks < 4; ++ks) {
        int k0 = ks * 32 + quad * 8;
        short8 a0, a1;
        if (self) {
            float4 z = {0.f, 0.f, 0.f, 0.f};
            float4 f00 = (r0 < n) ? *(const float4*)&feat[r0 * IN_F + k0] : z;
            float4 f01 = (r0 < n) ? *(const float4*)&feat[r0 * IN_F + k0 + 4] : z;
            float4 f10 = (r1 < n) ? *(const float4*)&feat[r1 * IN_F + k0] : z;
            float4 f11 = (r1 < n) ? *(const float4*)&feat[r1 * IN_F + k0 + 4] : z;
            union { short8 s; unsigned short u[8]; } ua, ub;
            ua.u[0] = f2bf(f00.x); ua.u[1] = f2bf(f00.y); ua.u[2] = f2bf(f00.z); ua.u[3] = f2bf(f00.w);
            ua.u[4] = f2bf(f01.x); ua.u[5] = f2bf(f01.y); ua.u[6] = f2bf(f01.z); ua.u[7] = f2bf(f01.w);
            ub.u[0] = f2bf(f10.x); ub.u[1] = f2bf(f10.y); ub.u[2] = f2bf(f10.z); ub.u[3] = f2bf(f10.w);
            ub.u[4] = f2bf(f11.x); ub.u[5] = f2bf(f11.y); ub.u[6] = f2bf(f11.z); ub.u[7] = f2bf(f11.w);
            a0 = ua.s; a1 = ub.s;
        } else {
            int lr0 = wave * 32 + lq;
            a0 = *(const short8*)&XSL[lr0 * XS_PAD + k0];
            a1 = *(const short8*)&XSL[(lr0 + 16) * XS_PAD + k0];
        }
#pragma unroll
        for (int nt = 0; nt < 8; ++nt) {
            short8 b = *(const short8*)&BL[(nt * 16 + lq) * BK_PAD + k0];
            acc0[nt] = __builtin_amdgcn_mfma_f32_16x16x32_bf16(a0, b, acc0[nt], 0, 0, 0);
            acc1[nt] = __builtin_amdgcn_mfma_f32_16x16x32_bf16(a1, b, acc1[nt], 0, 0, 0);
        }
    }

    if (self) {
#pragma unroll
        for (int nt = 0; nt < 8; ++nt) {
            int col = nt * 16 + lq;
            float bb = bias[col];
#pragma unroll
            for (int r = 0; r < 4; ++r) {
                int row = rowbase + quad * 4 + r;
                if (row < n) out[row * OUT_F + col] = acc0[nt][r] + bb;
                int row2 = row + 16;
                if (row2 < n) out[row2 * OUT_F + col] = acc1[nt][r] + bb;
            }
        }
    } else {
        // y stored row-major bf16: u32 at [node*64+l] = cols {2l (lo), 2l+1 (hi)}
#pragma unroll
        for (int nt = 0; nt < 8; ++nt) {
            int col = nt * 16 + lq;
#pragma unroll
            for (int r = 0; r < 4; ++r) {
                int row = rowbase + quad * 4 + r;
                if (row < n) y_bf[row * OUT_F + col] = f2bf(acc0[nt][r]);
                int row2 = row + 16;
                if (row2 < n) y_bf[row2 * OUT_F + col] = f2bf(acc1[nt][r]);
            }
        }
    }
}

// ---------------------------------------------------------------------------
// Kernel 2 (finalizer): out[d] += (1/deg) * sum y[src].  esrc rows are ushort,
// contiguous -> per-wave src batch is ONE coalesced 128B load. No atomics.
// ---------------------------------------------------------------------------
#define AGG_BLOCKS 2048
__global__ __launch_bounds__(256) void agg_out_kernel(
    const int* __restrict__ deg_pad, const unsigned short* __restrict__ esrc_pad,
    const unsigned* __restrict__ y_u, float* __restrict__ out, int n) {
    int wid = (blockIdx.x * 256 + threadIdx.x) >> 6;
    int l = threadIdx.x & 63;
    int nwaves = AGG_BLOCKS * 4;

    for (int d = wid; d < n; d += nwaves) {
        int bc_all = min(deg_pad[d << 4], MAXDEG);
        const unsigned short* row = esrc_pad + d * MAXDEG;
        float2 acc = {0.f, 0.f};
        {
            int bc = bc_all;
            int sv = (bc > 0) ? (int)row[min(l, bc - 1)] : 0;  // one coalesced batch load
            for (int r = 0; r < bc; r += 8) {
                unsigned uu[8];
                float mm[8];
#pragma unroll
                for (int q = 0; q < 8; ++q) {
                    int rr = r + q;
                    mm[q] = (rr < bc) ? 1.f : 0.f;
                    int s = __shfl(sv, min(rr, bc - 1));
                    uu[q] = y_u[s * 64 + l];
                }
#pragma unroll
                for (int q = 0; q < 8; ++q) {
                    acc.x += __uint_as_float(uu[q] << 16) * mm[q];
                    acc.y += __uint_as_float(uu[q] & 0xffff0000u) * mm[q];
                }
            }
        }
        float inv = 1.0f / (float)max(bc_all, 1);
        float2 cur = *(float2*)&out[d * OUT_F + 2 * l];
        cur.x += acc.x * inv;
        cur.y += acc.y * inv;
        *(float2*)&out[d * OUT_F + 2 * l] = cur;
    }
}

// ---------------------------------------------------------------------------
extern "C" void kernel_launch(void* const* d_in, const int* in_sizes, int n_in,
                              void* d_out, int out_size, void* d_ws, size_t ws_size,
                              hipStream_t stream) {
    const float* feat    = (const float*)d_in[0];
    const float* vals    = (const float*)d_in[1];
    const int*   idxs    = (const int*)d_in[2];
    const int*   src     = (const int*)d_in[3];
    const int*   dst     = (const int*)d_in[4];
    const float* W_self  = (const float*)d_in[5];
    const float* b_self  = (const float*)d_in[6];
    const float* W_neigh = (const float*)d_in[7];
    float*       out     = (float*)d_out;

    const int n = N_NODES;
    const int E = N_EDGES;

    // Workspace: [deg_pad N*16 int (3.2MB)][y_bf N*128 bf16 (12.8MB)]
    //            [esrc_pad N*64 u16 (6.4MB)]   total ~22.4 MB
    char* p = (char*)d_ws;
    int*            deg_pad  = (int*)p;            p += (size_t)n * 16 * sizeof(int);
    unsigned short* y_bf     = (unsigned short*)p; p += (size_t)n * OUT_F * sizeof(unsigned short);
    unsigned short* esrc_pad = (unsigned short*)p;

    hipMemsetAsync(deg_pad, 0, (size_t)n * 16 * sizeof(int), stream);

    gemm2_scatter_kernel<<<2 * GEMB, 256, 0, stream>>>(
        feat, W_self, b_self, out, vals, idxs, W_neigh, y_bf,
        src, dst, deg_pad, esrc_pad, n, E);
    agg_out_kernel<<<AGG_BLOCKS, 256, 0, stream>>>(
        deg_pad, esrc_pad, (const unsigned*)y_bf, out, n);
}